// Round 1
// baseline (795.379 us; speedup 1.0000x reference)
//
#include <hip/hip_runtime.h>

constexpr int IN_C  = 3;
constexpr int OUT_C = 64;
constexpr int NB    = 27;
constexpr int WFOLD = NB * IN_C * OUT_C;   // 5184

// ---- stage A: atomic segment sums (sx, sy, sz, count) per cluster ----
__global__ void k_accum(const float* __restrict__ x, const int* __restrict__ cluster,
                        float4* __restrict__ sums4, int N) {
    int stride = gridDim.x * blockDim.x;
    for (int n = blockIdx.x * blockDim.x + threadIdx.x; n < N; n += stride) {
        int c = cluster[n];
        float x0 = x[n * 3 + 0];
        float x1 = x[n * 3 + 1];
        float x2 = x[n * 3 + 2];
        float* s = reinterpret_cast<float*>(sums4 + c);
        atomicAdd(s + 0, x0);
        atomicAdd(s + 1, x1);
        atomicAdd(s + 2, x2);
        atomicAdd(s + 3, 1.0f);
    }
}

// ---- stage P: sums -> mean, in place ----
__global__ void k_pool(float4* sums4, int K) {
    int k = blockIdx.x * blockDim.x + threadIdx.x;
    if (k < K) {
        float4 s = sums4[k];
        float inv = 1.0f / fmaxf(s.w, 1.0f);
        sums4[k] = make_float4(s.x * inv, s.y * inv, s.z * inv, 0.0f);
    }
}

// ---- stage B: fold W_conv (27,3,64) with W_lin[3:,:] (64,64) -> Wc2 (27,3,64) ----
__global__ void k_fold(const float* __restrict__ Wc, const float* __restrict__ Wl,
                       float* __restrict__ Wc2) {
    int t = blockIdx.x * blockDim.x + threadIdx.x;
    if (t >= WFOLD) return;
    int j  = t & 63;      // output channel
    int oi = t >> 6;      // o*3 + i
    float acc = 0.f;
    #pragma unroll
    for (int j2 = 0; j2 < OUT_C; ++j2)
        acc = fmaf(Wc[oi * 64 + j2], Wl[(IN_C + j2) * OUT_C + j], acc);
    Wc2[t] = acc;
}

// ---- stage C: per-cluster v[k,j] = b[j] + sum_o pooled[nb[k,o]] . Wc2[o,:,j] ----
__global__ void k_conv(const int* __restrict__ nb, const float4* __restrict__ pooled4,
                       const float* __restrict__ Wc2, const float* __restrict__ b_lin,
                       float* __restrict__ v, int K) {
    __shared__ float wsm[WFOLD];   // 20736 B
    for (int t = threadIdx.x; t < WFOLD; t += blockDim.x) wsm[t] = Wc2[t];
    __syncthreads();

    int lane   = threadIdx.x & 63;
    int wid    = (blockIdx.x * blockDim.x + threadIdx.x) >> 6;
    int nwaves = (gridDim.x * blockDim.x) >> 6;
    float bl = b_lin[lane];

    for (int k = wid; k < K; k += nwaves) {
        const int* nbk = nb + k * NB;
        float acc = bl;
        #pragma unroll
        for (int o = 0; o < NB; ++o) {
            int idx = nbk[o];                 // wave-uniform
            if (idx >= 0) {                   // uniform branch
                float4 p = pooled4[idx];      // broadcast 16B
                const float* w = wsm + o * (IN_C * OUT_C) + lane;
                acc = fmaf(p.x, w[0],   acc);
                acc = fmaf(p.y, w[64],  acc);
                acc = fmaf(p.z, w[128], acc);
            }
        }
        v[(size_t)k * OUT_C + lane] = acc;
    }
}

// ---- stage D: u[n] = x[n] @ W_lin[0:3] + v[cluster[n]] ; 4 points/wave, float4 IO ----
__global__ void k_point(const float* __restrict__ x, const int* __restrict__ cluster,
                        const float* __restrict__ v, const float* __restrict__ Wl,
                        float* __restrict__ out, int N) {
    int lane = threadIdx.x & 63;
    int sub  = lane >> 4;            // which of 4 points in this wave
    int jj   = (lane & 15) * 4;      // 4 output channels per lane
    int gwid   = (blockIdx.x * blockDim.x + threadIdx.x) >> 6;
    int nwaves = (gridDim.x * blockDim.x) >> 6;

    float4 w0 = *reinterpret_cast<const float4*>(Wl + 0 * OUT_C + jj);
    float4 w1 = *reinterpret_cast<const float4*>(Wl + 1 * OUT_C + jj);
    float4 w2 = *reinterpret_cast<const float4*>(Wl + 2 * OUT_C + jj);

    for (int base = gwid * 4; base < N; base += nwaves * 4) {
        int n = base + sub;
        if (n < N) {
            int c  = cluster[n];
            float x0 = x[n * 3 + 0];
            float x1 = x[n * 3 + 1];
            float x2 = x[n * 3 + 2];
            float4 acc = *reinterpret_cast<const float4*>(v + (size_t)c * OUT_C + jj);
            acc.x = fmaf(x0, w0.x, fmaf(x1, w1.x, fmaf(x2, w2.x, acc.x)));
            acc.y = fmaf(x0, w0.y, fmaf(x1, w1.y, fmaf(x2, w2.y, acc.y)));
            acc.z = fmaf(x0, w0.z, fmaf(x1, w1.z, fmaf(x2, w2.z, acc.z)));
            acc.w = fmaf(x0, w0.w, fmaf(x1, w1.w, fmaf(x2, w2.w, acc.w)));
            *reinterpret_cast<float4*>(out + (size_t)n * OUT_C + jj) = acc;
        }
    }
}

extern "C" void kernel_launch(void* const* d_in, const int* in_sizes, int n_in,
                              void* d_out, int out_size, void* d_ws, size_t ws_size,
                              hipStream_t stream) {
    const float* x      = (const float*)d_in[0];
    const int*   cluster= (const int*)  d_in[1];
    const int*   nb     = (const int*)  d_in[2];
    const float* W_conv = (const float*)d_in[3];
    const float* W_lin  = (const float*)d_in[4];
    const float* b_lin  = (const float*)d_in[5];
    float* out = (float*)d_out;

    const int N = in_sizes[1];         // 1,000,000
    const int K = in_sizes[2] / NB;    // 200,000

    // workspace layout
    char* ws = (char*)d_ws;
    float4* sums4 = (float4*)ws;                       // K * 16 B   (3.2 MB)
    size_t off = (size_t)K * sizeof(float4);
    float* Wc2 = (float*)(ws + off);                   // 20736 B
    off += ((WFOLD * sizeof(float) + 255) / 256) * 256;
    float* v = (float*)(ws + off);                     // K * 64 * 4 B (51.2 MB)

    hipMemsetAsync(sums4, 0, (size_t)K * sizeof(float4), stream);

    k_fold <<<(WFOLD + 255) / 256, 256, 0, stream>>>(W_conv, W_lin, Wc2);
    k_accum<<<2048, 256, 0, stream>>>(x, cluster, sums4, N);
    k_pool <<<(K + 255) / 256, 256, 0, stream>>>(sums4, K);
    k_conv <<<2048, 256, 0, stream>>>(nb, sums4, Wc2, b_lin, v, K);
    k_point<<<2048, 256, 0, stream>>>(x, cluster, v, W_lin, out, N);
}

// Round 2
// 540.603 us; speedup vs baseline: 1.4713x; 1.4713x over previous
//
#include <hip/hip_runtime.h>

constexpr int IN_C  = 3;
constexpr int OUT_C = 64;
constexpr int NB    = 27;
constexpr int WFOLD = NB * IN_C * OUT_C;   // 5184

// ---- stage A: atomic segment sums (sx, sy, sz, count) per cluster ----
__global__ void k_accum(const float* __restrict__ x, const int* __restrict__ cluster,
                        float4* __restrict__ sums4, int N) {
    int stride = gridDim.x * blockDim.x;
    for (int n = blockIdx.x * blockDim.x + threadIdx.x; n < N; n += stride) {
        int c = cluster[n];
        float x0 = x[n * 3 + 0];
        float x1 = x[n * 3 + 1];
        float x2 = x[n * 3 + 2];
        float* s = reinterpret_cast<float*>(sums4 + c);
        atomicAdd(s + 0, x0);
        atomicAdd(s + 1, x1);
        atomicAdd(s + 2, x2);
        atomicAdd(s + 3, 1.0f);
    }
}

// ---- stage P: sums -> mean, in place; also writes zero sentinel row at K ----
__global__ void k_pool(float4* sums4, int K) {
    int k = blockIdx.x * blockDim.x + threadIdx.x;
    if (k < K) {
        float4 s = sums4[k];
        float inv = 1.0f / fmaxf(s.w, 1.0f);
        sums4[k] = make_float4(s.x * inv, s.y * inv, s.z * inv, 0.0f);
    } else if (k == K) {
        sums4[K] = make_float4(0.f, 0.f, 0.f, 0.f);   // sentinel for masked neighbors
    }
}

// ---- stage B: fold W_conv (27,3,64) with W_lin[3:,:] (64,64) -> Wc2 (27,3,64) ----
__global__ void k_fold(const float* __restrict__ Wc, const float* __restrict__ Wl,
                       float* __restrict__ Wc2) {
    int t = blockIdx.x * blockDim.x + threadIdx.x;
    if (t >= WFOLD) return;
    int j  = t & 63;      // output channel
    int oi = t >> 6;      // o*3 + i
    float acc = 0.f;
    #pragma unroll
    for (int j2 = 0; j2 < OUT_C; ++j2)
        acc = fmaf(Wc[oi * 64 + j2], Wl[(IN_C + j2) * OUT_C + j], acc);
    Wc2[t] = acc;
}

// ---- stage C: per-cluster v[k,j] = b[j] + sum_o pooled[nb[k,o]] . Wc2[o,:,j] ----
// One wave per cluster; lane = output channel. Weights live in 81 VGPRs.
// Branch-free: idx<0 maps (via unsigned min) to the zero sentinel row at K.
__global__ __launch_bounds__(256) void
k_conv(const int* __restrict__ nb, const float4* __restrict__ pooled4,
       const float* __restrict__ Wc2, const float* __restrict__ b_lin,
       float* __restrict__ v, int K) {
    int lane   = threadIdx.x & 63;
    int wid    = (blockIdx.x * blockDim.x + threadIdx.x) >> 6;
    int nwaves = (gridDim.x * blockDim.x) >> 6;

    // per-lane weight column: w[o*3+i] = Wc2[(o*3+i)*64 + lane]
    float w[NB * IN_C];
    #pragma unroll
    for (int t = 0; t < NB * IN_C; ++t) w[t] = Wc2[t * OUT_C + lane];
    float bl = b_lin[lane];
    unsigned uK = (unsigned)K;

    for (int k = wid; k < K; k += nwaves) {
        const int* nbk = nb + (size_t)k * NB;

        // 1) issue all 27 index loads (wave-uniform addresses -> broadcast)
        int idx[NB];
        #pragma unroll
        for (int o = 0; o < NB; ++o) idx[o] = nbk[o];

        // 2) issue all 27 pooled gathers (independent, high MLP)
        float4 p[NB];
        #pragma unroll
        for (int o = 0; o < NB; ++o) {
            unsigned safe = min((unsigned)idx[o], uK);   // -1 -> 0xFFFFFFFF -> K (zero row)
            p[o] = pooled4[safe];
        }

        // 3) 81 FMAs, 3 independent accumulator chains
        float a0 = bl, a1 = 0.f, a2 = 0.f;
        #pragma unroll
        for (int o = 0; o < NB; ++o) {
            a0 = fmaf(p[o].x, w[o * 3 + 0], a0);
            a1 = fmaf(p[o].y, w[o * 3 + 1], a1);
            a2 = fmaf(p[o].z, w[o * 3 + 2], a2);
        }
        v[(size_t)k * OUT_C + lane] = a0 + a1 + a2;
    }
}

// ---- stage D: u[n] = x[n] @ W_lin[0:3] + v[cluster[n]] ; 4 points/wave, float4 IO ----
__global__ void k_point(const float* __restrict__ x, const int* __restrict__ cluster,
                        const float* __restrict__ v, const float* __restrict__ Wl,
                        float* __restrict__ out, int N) {
    int lane = threadIdx.x & 63;
    int sub  = lane >> 4;            // which of 4 points in this wave
    int jj   = (lane & 15) * 4;      // 4 output channels per lane
    int gwid   = (blockIdx.x * blockDim.x + threadIdx.x) >> 6;
    int nwaves = (gridDim.x * blockDim.x) >> 6;

    float4 w0 = *reinterpret_cast<const float4*>(Wl + 0 * OUT_C + jj);
    float4 w1 = *reinterpret_cast<const float4*>(Wl + 1 * OUT_C + jj);
    float4 w2 = *reinterpret_cast<const float4*>(Wl + 2 * OUT_C + jj);

    for (int base = gwid * 4; base < N; base += nwaves * 4) {
        int n = base + sub;
        if (n < N) {
            int c  = cluster[n];
            float x0 = x[n * 3 + 0];
            float x1 = x[n * 3 + 1];
            float x2 = x[n * 3 + 2];
            float4 acc = *reinterpret_cast<const float4*>(v + (size_t)c * OUT_C + jj);
            acc.x = fmaf(x0, w0.x, fmaf(x1, w1.x, fmaf(x2, w2.x, acc.x)));
            acc.y = fmaf(x0, w0.y, fmaf(x1, w1.y, fmaf(x2, w2.y, acc.y)));
            acc.z = fmaf(x0, w0.z, fmaf(x1, w1.z, fmaf(x2, w2.z, acc.z)));
            acc.w = fmaf(x0, w0.w, fmaf(x1, w1.w, fmaf(x2, w2.w, acc.w)));
            *reinterpret_cast<float4*>(out + (size_t)n * OUT_C + jj) = acc;
        }
    }
}

extern "C" void kernel_launch(void* const* d_in, const int* in_sizes, int n_in,
                              void* d_out, int out_size, void* d_ws, size_t ws_size,
                              hipStream_t stream) {
    const float* x      = (const float*)d_in[0];
    const int*   cluster= (const int*)  d_in[1];
    const int*   nb     = (const int*)  d_in[2];
    const float* W_conv = (const float*)d_in[3];
    const float* W_lin  = (const float*)d_in[4];
    const float* b_lin  = (const float*)d_in[5];
    float* out = (float*)d_out;

    const int N = in_sizes[1];         // 1,000,000
    const int K = in_sizes[2] / NB;    // 200,000

    // workspace layout
    char* ws = (char*)d_ws;
    float4* sums4 = (float4*)ws;                       // (K+1) * 16 B  (zero sentinel row at K)
    size_t off = (size_t)(K + 1) * sizeof(float4);
    off = ((off + 255) / 256) * 256;
    float* Wc2 = (float*)(ws + off);                   // 20736 B
    off += ((WFOLD * sizeof(float) + 255) / 256) * 256;
    float* v = (float*)(ws + off);                     // K * 64 * 4 B (51.2 MB)

    hipMemsetAsync(sums4, 0, (size_t)K * sizeof(float4), stream);

    k_fold <<<(WFOLD + 255) / 256, 256, 0, stream>>>(W_conv, W_lin, Wc2);
    k_accum<<<2048, 256, 0, stream>>>(x, cluster, sums4, N);
    k_pool <<<(K + 1 + 255) / 256, 256, 0, stream>>>(sums4, K);
    k_conv <<<2048, 256, 0, stream>>>(nb, sums4, Wc2, b_lin, v, K);
    k_point<<<2048, 256, 0, stream>>>(x, cluster, v, W_lin, out, N);
}

// Round 3
// 457.374 us; speedup vs baseline: 1.7390x; 1.1820x over previous
//
#include <hip/hip_runtime.h>

constexpr int IN_C   = 3;
constexpr int OUT_C  = 64;
constexpr int NB     = 27;
constexpr int WROW   = 84;               // 81 padded to 84 (16B-aligned rows)
constexpr int WFOLDT = OUT_C * WROW;     // 5376

// ---- stage A: atomic segment sums (sx, sy, sz, count) per cluster ----
__global__ void k_accum(const float* __restrict__ x, const int* __restrict__ cluster,
                        float4* __restrict__ sums4, int N) {
    int stride = gridDim.x * blockDim.x;
    for (int n = blockIdx.x * blockDim.x + threadIdx.x; n < N; n += stride) {
        int c = cluster[n];
        float x0 = x[n * 3 + 0];
        float x1 = x[n * 3 + 1];
        float x2 = x[n * 3 + 2];
        float* s = reinterpret_cast<float*>(sums4 + c);
        atomicAdd(s + 0, x0);
        atomicAdd(s + 1, x1);
        atomicAdd(s + 2, x2);
        atomicAdd(s + 3, 1.0f);
    }
}

// ---- stage P: sums -> mean, in place; zero sentinel row at K ----
__global__ void k_pool(float4* sums4, int K) {
    int k = blockIdx.x * blockDim.x + threadIdx.x;
    if (k < K) {
        float4 s = sums4[k];
        float inv = 1.0f / fmaxf(s.w, 1.0f);
        sums4[k] = make_float4(s.x * inv, s.y * inv, s.z * inv, 0.0f);
    } else if (k == K) {
        sums4[K] = make_float4(0.f, 0.f, 0.f, 0.f);
    }
}

// ---- stage B: fold W_conv with W_lin[3:,:], TRANSPOSED: WcT[j*84 + (o*3+i)] ----
__global__ void k_fold(const float* __restrict__ Wc, const float* __restrict__ Wl,
                       float* __restrict__ WcT) {
    int t = blockIdx.x * blockDim.x + threadIdx.x;
    if (t >= WFOLDT) return;
    int j = t / WROW;
    int f = t % WROW;     // f = o*3+i
    float acc = 0.f;
    if (f < NB * IN_C) {
        #pragma unroll
        for (int j2 = 0; j2 < OUT_C; ++j2)
            acc = fmaf(Wc[f * 64 + j2], Wl[(IN_C + j2) * OUT_C + j], acc);
    }
    WcT[t] = acc;
}

// ---- stage C: cluster-parallel. lane = cluster, loop over 64 channels. ----
// Each lane gathers its own cluster's 27 pooled rows (divergent -> 1728
// requests in flight per wave). Weights are wave-uniform loads from a 21KB
// L1-resident table. Output transposed through per-wave LDS, stored coalesced.
__global__ __launch_bounds__(256) void
k_conv(const int* __restrict__ nb, const float4* __restrict__ pooled4,
       const float* __restrict__ WcT, const float* __restrict__ b_lin,
       float* __restrict__ v, int K) {
    __shared__ float xpose[4 * 64 * 17];     // 17408 B, per-wave slices
    const int lane = threadIdx.x & 63;
    const int wv   = threadIdx.x >> 6;
    const int wid  = (blockIdx.x * blockDim.x + threadIdx.x) >> 6;
    const int base = wid * 64;
    if (base >= K) return;
    const int kme = min(base + lane, K - 1);

    const int* nbrow = nb + (size_t)kme * NB;
    const unsigned uK = (unsigned)K;

    // 27 per-lane gathers; -1 maps (unsigned min) to zero sentinel row at K
    float4 p[NB];
    #pragma unroll
    for (int o = 0; o < NB; ++o) {
        unsigned s = min((unsigned)nbrow[o], uK);
        p[o] = pooled4[s];
    }

    float* xb = xpose + wv * (64 * 17);
    const int c4 = lane >> 4, jloc = lane & 15;

    #pragma unroll 1
    for (int jb = 0; jb < 4; ++jb) {
        #pragma unroll 2
        for (int jl = 0; jl < 16; ++jl) {
            const int j = jb * 16 + jl;
            const float* __restrict__ wj = WcT + j * WROW;   // wave-uniform row
            float a0 = b_lin[j], a1 = 0.f, a2 = 0.f;
            #pragma unroll
            for (int o = 0; o < NB; ++o) {
                a0 = fmaf(p[o].x, wj[o * 3 + 0], a0);
                a1 = fmaf(p[o].y, wj[o * 3 + 1], a1);
                a2 = fmaf(p[o].z, wj[o * 3 + 2], a2);
            }
            xb[lane * 17 + jl] = a0 + a1 + a2;               // 2-way banks: free
        }
        // transpose store: 16 coalesced 256B store instrs per jb
        #pragma unroll
        for (int cg = 0; cg < 16; ++cg) {
            int cl = cg * 4 + c4;
            int kk = base + cl;
            if (kk < K)
                v[(size_t)kk * OUT_C + jb * 16 + jloc] = xb[cl * 17 + jloc];
        }
    }
}

// ---- stage D: u[n] = x[n] @ W_lin[0:3] + v[cluster[n]] ; 4 pts/wave, float4 IO ----
__global__ void k_point(const float* __restrict__ x, const int* __restrict__ cluster,
                        const float* __restrict__ v, const float* __restrict__ Wl,
                        float* __restrict__ out, int N) {
    int lane = threadIdx.x & 63;
    int sub  = lane >> 4;
    int jj   = (lane & 15) * 4;
    int gwid   = (blockIdx.x * blockDim.x + threadIdx.x) >> 6;
    int nwaves = (gridDim.x * blockDim.x) >> 6;

    float4 w0 = *reinterpret_cast<const float4*>(Wl + 0 * OUT_C + jj);
    float4 w1 = *reinterpret_cast<const float4*>(Wl + 1 * OUT_C + jj);
    float4 w2 = *reinterpret_cast<const float4*>(Wl + 2 * OUT_C + jj);

    for (int base = gwid * 4; base < N; base += nwaves * 4) {
        int n = base + sub;
        if (n < N) {
            int c  = cluster[n];
            float x0 = x[n * 3 + 0];
            float x1 = x[n * 3 + 1];
            float x2 = x[n * 3 + 2];
            float4 acc = *reinterpret_cast<const float4*>(v + (size_t)c * OUT_C + jj);
            acc.x = fmaf(x0, w0.x, fmaf(x1, w1.x, fmaf(x2, w2.x, acc.x)));
            acc.y = fmaf(x0, w0.y, fmaf(x1, w1.y, fmaf(x2, w2.y, acc.y)));
            acc.z = fmaf(x0, w0.z, fmaf(x1, w1.z, fmaf(x2, w2.z, acc.z)));
            acc.w = fmaf(x0, w0.w, fmaf(x1, w1.w, fmaf(x2, w2.w, acc.w)));
            *reinterpret_cast<float4*>(out + (size_t)n * OUT_C + jj) = acc;
        }
    }
}

extern "C" void kernel_launch(void* const* d_in, const int* in_sizes, int n_in,
                              void* d_out, int out_size, void* d_ws, size_t ws_size,
                              hipStream_t stream) {
    const float* x      = (const float*)d_in[0];
    const int*   cluster= (const int*)  d_in[1];
    const int*   nb     = (const int*)  d_in[2];
    const float* W_conv = (const float*)d_in[3];
    const float* W_lin  = (const float*)d_in[4];
    const float* b_lin  = (const float*)d_in[5];
    float* out = (float*)d_out;

    const int N = in_sizes[1];         // 1,000,000
    const int K = in_sizes[2] / NB;    // 200,000

    // workspace layout
    char* ws = (char*)d_ws;
    float4* sums4 = (float4*)ws;                       // (K+1) * 16 B (sentinel at K)
    size_t off = (size_t)(K + 1) * sizeof(float4);
    off = ((off + 255) / 256) * 256;
    float* WcT = (float*)(ws + off);                   // 21504 B
    off += ((WFOLDT * sizeof(float) + 255) / 256) * 256;
    float* v = (float*)(ws + off);                     // K * 64 * 4 B (51.2 MB)

    hipMemsetAsync(sums4, 0, (size_t)K * sizeof(float4), stream);

    k_fold <<<(WFOLDT + 255) / 256, 256, 0, stream>>>(W_conv, W_lin, WcT);
    k_accum<<<2048, 256, 0, stream>>>(x, cluster, sums4, N);
    k_pool <<<(K + 1 + 255) / 256, 256, 0, stream>>>(sums4, K);

    int conv_waves  = (K + 63) / 64;                   // 3125
    int conv_blocks = (conv_waves + 3) / 4;            // 782
    k_conv <<<conv_blocks, 256, 0, stream>>>(nb, sums4, WcT, b_lin, v, K);

    k_point<<<2048, 256, 0, stream>>>(x, cluster, v, W_lin, out, N);
}